// Round 1
// baseline (449.797 us; speedup 1.0000x reference)
//
#include <hip/hip_runtime.h>
#include <math.h>

// ---------------- workspace layout (float offsets) ----------------
#define WS_P  0         // P[4][128*128]  pair products
#define WS_Q0 65536     // Wa0..3 product
#define WS_Q1 81920     // Wa4..7 product
#define WS_R  98304     // Wa4*Wa5*Wa6
#define WS_WT 114688    // W~[8][128*128]
#define WS_WU 245760    // WU[k][i*128+h] = W~_i[h][k]   (128 x 1024)
#define WS_ZT 376832    // ZT[k'][i*128+h] = (W~_i*Wo_i)[h][k'] (128 x 1024)
#define WS_Z0 507904    // z0[128]
#define WS_U  524288    // U/S [8192][1024]  (u then overwritten by s)
// total floats: 524288 + 8388608 = 8912896  (35.65 MB)

struct MMJob { const float* A; const float* B; float* C; float* wu; };
struct MMArgs { MMJob j[8]; };

// C = A @ B for 128x128 matrices; if A==nullptr, C = B (copy).
// Optional transposed store: wu[col*1024 + row] = C[row][col].
// grid = njobs*4, block = 256. Each block: 32 rows x 128 cols.
__global__ __launch_bounds__(256) void mm128_jobs(MMArgs args) {
  const int job = blockIdx.x >> 2;
  const int tile = blockIdx.x & 3;
  const MMJob J = args.j[job];
  const int t = threadIdx.x;
  const int col = t & 127;
  const int rg = t >> 7;

  if (J.A == nullptr) {
    for (int rr = 0; rr < 16; ++rr) {
      const int r = tile * 32 + rg * 16 + rr;
      const float v = J.B[r * 128 + col];
      if (J.C) J.C[r * 128 + col] = v;
      if (J.wu) J.wu[col * 1024 + r] = v;
    }
    return;
  }

  __shared__ float Al[32 * 128];
  for (int jj = 0; jj < 16; ++jj) {
    const int idx = t + jj * 256;
    Al[idx] = J.A[tile * 32 * 128 + idx];
  }
  __syncthreads();

  float acc[16];
#pragma unroll
  for (int rr = 0; rr < 16; ++rr) acc[rr] = 0.f;
  for (int h = 0; h < 128; ++h) {
    const float bv = J.B[h * 128 + col];
#pragma unroll
    for (int rr = 0; rr < 16; ++rr)
      acc[rr] = fmaf(Al[(rg * 16 + rr) * 128 + h], bv, acc[rr]);
  }
#pragma unroll
  for (int rr = 0; rr < 16; ++rr) {
    const int r = tile * 32 + rg * 16 + rr;
    if (J.C) J.C[r * 128 + col] = acc[rr];
    if (J.wu) J.wu[col * 1024 + r] = acc[rr];
  }
}

// b~ chain + z0 = bo + sum_i b~_i @ Wo_i.  1 block x 128 threads.
__global__ __launch_bounds__(128) void bias_z0_k(
    const float* __restrict__ Wa, const float* __restrict__ ba,
    const float* __restrict__ Wo, const float* __restrict__ bo,
    float* __restrict__ z0) {
  __shared__ float bt[8][128];
  const int t = threadIdx.x;
  bt[0][t] = ba[t];
  __syncthreads();
  for (int i = 1; i < 8; ++i) {
    float v = ba[i * 128 + t];
    for (int h = 0; h < 128; ++h)
      v = fmaf(bt[i - 1][h], Wa[i * 16384 + h * 128 + t], v);
    bt[i][t] = v;
    __syncthreads();
  }
  float z = bo[t];
  for (int i = 0; i < 8; ++i)
    for (int h = 0; h < 128; ++h)
      z = fmaf(bt[i][h], Wo[(i * 128 + h) * 128 + t], z);
  z0[t] = z;
}

// U[b][c] = sum_k V[b][k] * WU[k][c].  grid = 128 btiles * 8 ctiles.
__global__ __launch_bounds__(256) void gemm_U_k(
    const float* __restrict__ V, const float* __restrict__ WU,
    float* __restrict__ U) {
  const int btile = blockIdx.x >> 3;
  const int ctile = blockIdx.x & 7;
  const int t = threadIdx.x;
  __shared__ float Vl[64 * 128];
#pragma unroll
  for (int jj = 0; jj < 8; ++jj) {
    const int i4 = t + jj * 256;
    ((float4*)Vl)[i4] = ((const float4*)(V + (size_t)btile * 64 * 128))[i4];
  }
  __syncthreads();
  const int cg = t & 31;
  const int rg = t >> 5;
  float4 acc[8];
#pragma unroll
  for (int r8 = 0; r8 < 8; ++r8) acc[r8] = make_float4(0.f, 0.f, 0.f, 0.f);
  const float* wu = WU + ctile * 128 + cg * 4;
  for (int k = 0; k < 128; ++k) {
    const float4 w4 = *(const float4*)&wu[(size_t)k * 1024];
#pragma unroll
    for (int r8 = 0; r8 < 8; ++r8) {
      const float a = Vl[(rg * 8 + r8) * 128 + k];
      acc[r8].x = fmaf(a, w4.x, acc[r8].x);
      acc[r8].y = fmaf(a, w4.y, acc[r8].y);
      acc[r8].z = fmaf(a, w4.z, acc[r8].z);
      acc[r8].w = fmaf(a, w4.w, acc[r8].w);
    }
  }
#pragma unroll
  for (int r8 = 0; r8 < 8; ++r8)
    *(float4*)&U[(size_t)(btile * 64 + rg * 8 + r8) * 1024 + ctile * 128 + cg * 4] = acc[r8];
}

// Per-batch: e_i[n] = q0[n,:].u_i ; softmax over n ; s_i = sum_n sc_i[n] q0[n,:].
// Reads u from U[b], writes s over U[b] (in place). One block per batch.
__global__ __launch_bounds__(256) void attn_main_k(
    const float* __restrict__ query, const float* __restrict__ value,
    float* U) {
  const int b = blockIdx.x;
  const int t = threadIdx.x;
  __shared__ float q0s[65 * 132];  // padded stride 132
  __shared__ float es[8 * 66];     // logits, then normalized scores (in place)
  __shared__ float shu[4096];      // u[1024] during e-pass; spart[4][8][128] during s-pass

  // ---- stage q0 (query rows 0..63, value row 64) and u ----
  {
    const float4* qsrc = (const float4*)(query + (size_t)b * 8192);
#pragma unroll
    for (int jj = 0; jj < 8; ++jj) {
      const int i4 = t + jj * 256;
      const int row = i4 >> 5, c4 = i4 & 31;
      *(float4*)&q0s[row * 132 + c4 * 4] = qsrc[i4];
    }
    if (t < 32)
      *(float4*)&q0s[64 * 132 + t * 4] = ((const float4*)(value + (size_t)b * 128))[t];
    *(float4*)&shu[t * 4] = ((const float4*)(U + (size_t)b * 1024))[t];
  }
  __syncthreads();

  // ---- e-pass: 4 lanes per row (h-quarters), 8 heads in registers ----
  {
    const int qq = t & 3;
    const int n = t >> 2;
    float acc[8] = {0.f, 0.f, 0.f, 0.f, 0.f, 0.f, 0.f, 0.f};
    const float* qrow = &q0s[n * 132 + qq * 32];
#pragma unroll
    for (int hc = 0; hc < 8; ++hc) {
      const float4 q4 = *(const float4*)&qrow[hc * 4];
#pragma unroll
      for (int i = 0; i < 8; ++i) {
        const float4 u4 = *(const float4*)&shu[i * 128 + qq * 32 + hc * 4];
        acc[i] = fmaf(q4.x, u4.x, acc[i]);
        acc[i] = fmaf(q4.y, u4.y, acc[i]);
        acc[i] = fmaf(q4.z, u4.z, acc[i]);
        acc[i] = fmaf(q4.w, u4.w, acc[i]);
      }
    }
#pragma unroll
    for (int i = 0; i < 8; ++i) {
      float v = acc[i];
      v += __shfl_xor(v, 1, 4);
      v += __shfl_xor(v, 2, 4);
      if (qq == 0) es[i * 66 + n] = v;
    }
    if (t < 4) {  // row 64 (the value row)
      const int qq2 = t;
      float acc2[8] = {0.f, 0.f, 0.f, 0.f, 0.f, 0.f, 0.f, 0.f};
      const float* qrow2 = &q0s[64 * 132 + qq2 * 32];
#pragma unroll
      for (int hc = 0; hc < 8; ++hc) {
        const float4 q4 = *(const float4*)&qrow2[hc * 4];
#pragma unroll
        for (int i = 0; i < 8; ++i) {
          const float4 u4 = *(const float4*)&shu[i * 128 + qq2 * 32 + hc * 4];
          acc2[i] = fmaf(q4.x, u4.x, acc2[i]);
          acc2[i] = fmaf(q4.y, u4.y, acc2[i]);
          acc2[i] = fmaf(q4.z, u4.z, acc2[i]);
          acc2[i] = fmaf(q4.w, u4.w, acc2[i]);
        }
      }
#pragma unroll
      for (int i = 0; i < 8; ++i) {
        float v = acc2[i];
        v += __shfl_xor(v, 1, 4);
        v += __shfl_xor(v, 2, 4);
        if (qq2 == 0) es[i * 66 + 64] = v;
      }
    }
  }
  __syncthreads();

  // ---- softmax: 4 waves x 2 heads, 65 values each ----
  {
    const int wv = t >> 6;
    const int l = t & 63;
    for (int ii = 0; ii < 2; ++ii) {
      const int i = wv * 2 + ii;
      const float x = es[i * 66 + l];
      const float x64 = es[i * 66 + 64];
      float m = x;
#pragma unroll
      for (int d = 1; d < 64; d <<= 1) m = fmaxf(m, __shfl_xor(m, d, 64));
      m = fmaxf(m, x64);
      const float p = expf(x - m);
      const float p64 = expf(x64 - m);
      float ssum = p;
#pragma unroll
      for (int d = 1; d < 64; d <<= 1) ssum += __shfl_xor(ssum, d, 64);
      ssum += p64;
      const float inv = 1.0f / ssum;
      es[i * 66 + l] = p * inv;
      if (l == 0) es[i * 66 + 64] = p64 * inv;
    }
  }
  __syncthreads();

  // ---- s-pass: thread = (h-chunk, i-half, n-group); partials in shu ----
  {
    const int hc = t & 31;
    const int ih = (t >> 5) & 1;
    const int ng = t >> 6;
    float4 a0 = make_float4(0.f, 0.f, 0.f, 0.f), a1 = a0, a2 = a0, a3 = a0;
    const int n0 = (ng == 0) ? 0 : ng * 16 + 1;
    const int n1 = ng * 16 + 16;
    for (int n = n0; n <= n1; ++n) {
      const float4 q4 = *(const float4*)&q0s[n * 132 + hc * 4];
      const float s0 = es[(ih * 4 + 0) * 66 + n];
      const float s1 = es[(ih * 4 + 1) * 66 + n];
      const float s2 = es[(ih * 4 + 2) * 66 + n];
      const float s3 = es[(ih * 4 + 3) * 66 + n];
      a0.x = fmaf(s0, q4.x, a0.x); a0.y = fmaf(s0, q4.y, a0.y);
      a0.z = fmaf(s0, q4.z, a0.z); a0.w = fmaf(s0, q4.w, a0.w);
      a1.x = fmaf(s1, q4.x, a1.x); a1.y = fmaf(s1, q4.y, a1.y);
      a1.z = fmaf(s1, q4.z, a1.z); a1.w = fmaf(s1, q4.w, a1.w);
      a2.x = fmaf(s2, q4.x, a2.x); a2.y = fmaf(s2, q4.y, a2.y);
      a2.z = fmaf(s2, q4.z, a2.z); a2.w = fmaf(s2, q4.w, a2.w);
      a3.x = fmaf(s3, q4.x, a3.x); a3.y = fmaf(s3, q4.y, a3.y);
      a3.z = fmaf(s3, q4.z, a3.z); a3.w = fmaf(s3, q4.w, a3.w);
    }
    *(float4*)&shu[(ng * 8 + ih * 4 + 0) * 128 + hc * 4] = a0;
    *(float4*)&shu[(ng * 8 + ih * 4 + 1) * 128 + hc * 4] = a1;
    *(float4*)&shu[(ng * 8 + ih * 4 + 2) * 128 + hc * 4] = a2;
    *(float4*)&shu[(ng * 8 + ih * 4 + 3) * 128 + hc * 4] = a3;
    __syncthreads();
    float4 r = make_float4(0.f, 0.f, 0.f, 0.f);
    const int io = t >> 5;
    const int h4 = (t & 31) * 4;
#pragma unroll
    for (int g = 0; g < 4; ++g) {
      const float4 p = *(const float4*)&shu[(g * 8 + io) * 128 + h4];
      r.x += p.x; r.y += p.y; r.z += p.z; r.w += p.w;
    }
    ((float4*)(U + (size_t)b * 1024))[t] = r;  // S written over U
  }
}

// out[b][k'] = relu(z0[k'] + sum_c S[b][c] * ZT[k'][c]).  16 batches/block.
__global__ __launch_bounds__(256) void gemm_out_k(
    const float* __restrict__ S, const float* __restrict__ ZT,
    const float* __restrict__ z0, float* __restrict__ out) {
  const int bt0 = blockIdx.x * 16;
  const int t = threadIdx.x;
  const int col = t & 127;
  const int rg = t >> 7;
  __shared__ float Sl[16 * 128];
  float acc[8] = {0.f, 0.f, 0.f, 0.f, 0.f, 0.f, 0.f, 0.f};
  for (int kc = 0; kc < 8; ++kc) {
    __syncthreads();
#pragma unroll
    for (int jj = 0; jj < 2; ++jj) {
      const int i4 = t + jj * 256;
      const int row = i4 >> 5, c4 = i4 & 31;
      *(float4*)&Sl[row * 128 + c4 * 4] =
          *(const float4*)&S[(size_t)(bt0 + row) * 1024 + kc * 128 + c4 * 4];
    }
    __syncthreads();
    const float4* zt = (const float4*)&ZT[(size_t)col * 1024 + kc * 128];
    for (int k4 = 0; k4 < 32; ++k4) {
      const float4 z4 = zt[k4];
#pragma unroll
      for (int r = 0; r < 8; ++r) {
        const float4 s4 = *(const float4*)&Sl[(rg * 8 + r) * 128 + k4 * 4];
        acc[r] = fmaf(s4.x, z4.x, acc[r]);
        acc[r] = fmaf(s4.y, z4.y, acc[r]);
        acc[r] = fmaf(s4.z, z4.z, acc[r]);
        acc[r] = fmaf(s4.w, z4.w, acc[r]);
      }
    }
  }
  const float zz = z0[col];
#pragma unroll
  for (int r = 0; r < 8; ++r) {
    const float v = acc[r] + zz;
    out[(size_t)(bt0 + rg * 8 + r) * 128 + col] = fmaxf(v, 0.f);
  }
}

extern "C" void kernel_launch(void* const* d_in, const int* in_sizes, int n_in,
                              void* d_out, int out_size, void* d_ws, size_t ws_size,
                              hipStream_t stream) {
  const float* query = (const float*)d_in[0];
  const float* value = (const float*)d_in[1];
  const float* Wa    = (const float*)d_in[2];
  const float* ba    = (const float*)d_in[3];
  const float* Wo    = (const float*)d_in[4];
  const float* bo    = (const float*)d_in[5];
  float* ws = (float*)d_ws;
  float* P  = ws + WS_P;
  float* Q0 = ws + WS_Q0;
  float* Q1 = ws + WS_Q1;
  float* R  = ws + WS_R;
  float* WT = ws + WS_WT;
  float* WU = ws + WS_WU;
  float* ZT = ws + WS_ZT;
  float* Z0 = ws + WS_Z0;
  float* U  = ws + WS_U;

  // level 1: pair products P_j = Wa_{2j} @ Wa_{2j+1}
  MMArgs a1{};
  for (int j = 0; j < 4; ++j)
    a1.j[j] = MMJob{Wa + 2 * j * 16384, Wa + (2 * j + 1) * 16384, P + j * 16384, nullptr};
  mm128_jobs<<<16, 256, 0, stream>>>(a1);

  // level 2: Q0 = P0@P1 (Wa0..3), Q1 = P2@P3 (Wa4..7), R = P2@Wa6
  MMArgs a2{};
  a2.j[0] = MMJob{P, P + 16384, Q0, nullptr};
  a2.j[1] = MMJob{P + 2 * 16384, P + 3 * 16384, Q1, nullptr};
  a2.j[2] = MMJob{P + 2 * 16384, Wa + 6 * 16384, R, nullptr};
  mm128_jobs<<<12, 256, 0, stream>>>(a2);

  // level 3: all prefixes W~_i (+ transposed store into WU for gemm_U)
  MMArgs a3{};
  a3.j[0] = MMJob{nullptr, Wa,             WT + 0 * 16384, WU + 0 * 128};
  a3.j[1] = MMJob{nullptr, P,              WT + 1 * 16384, WU + 1 * 128};
  a3.j[2] = MMJob{P,       Wa + 2 * 16384, WT + 2 * 16384, WU + 2 * 128};
  a3.j[3] = MMJob{nullptr, Q0,             WT + 3 * 16384, WU + 3 * 128};
  a3.j[4] = MMJob{Q0,      Wa + 4 * 16384, WT + 4 * 16384, WU + 4 * 128};
  a3.j[5] = MMJob{Q0,      P + 2 * 16384,  WT + 5 * 16384, WU + 5 * 128};
  a3.j[6] = MMJob{Q0,      R,              WT + 6 * 16384, WU + 6 * 128};
  a3.j[7] = MMJob{Q0,      Q1,             WT + 7 * 16384, WU + 7 * 128};
  mm128_jobs<<<32, 256, 0, stream>>>(a3);

  // level 4: ZT (transposed store of W~_i @ Wo_i)
  MMArgs a4{};
  for (int i = 0; i < 8; ++i)
    a4.j[i] = MMJob{WT + i * 16384, Wo + i * 16384, nullptr, ZT + i * 128};
  mm128_jobs<<<32, 256, 0, stream>>>(a4);

  bias_z0_k<<<1, 128, 0, stream>>>(Wa, ba, Wo, bo, Z0);
  gemm_U_k<<<1024, 256, 0, stream>>>(value, WU, U);
  attn_main_k<<<8192, 256, 0, stream>>>(query, value, U);
  gemm_out_k<<<512, 256, 0, stream>>>(U, ZT, Z0, (float*)d_out);
}